// Round 1
// baseline (2370.370 us; speedup 1.0000x reference)
//
#include <hip/hip_runtime.h>
#include <hip/hip_bf16.h>

// Problem constants
#define B_ROWS 2048
#define UDIM   10000
#define XDIM   20000
#define KTOT   50000   // 2*XDIM + UDIM
#define NF     128

// Workspace layout (floats):
//   vv [KTOT], tt [KTOT], vt [KTOT]
//   G  [3 segments][B_ROWS][256]   (seg 0 = shared (u+x_prev), 1 = pos, 2 = neg; cols 0..127 = @V, 128..255 = @T)
//   S  [4 sources][B_ROWS][5]      (src 0=u,1=x_prev,2=x_pos,3=x_neg; vals: a@vv, a@tt, a@vt, a@W, sum(a))

__device__ inline void atomic_add_f32(float* p, float v) {
#if defined(__AMDGCN__)
    unsafeAtomicAdd(p, v);
#else
    atomicAdd(p, v);
#endif
}

// ---------------------------------------------------------------------------
// vv[k] = sum_j V[k,j]^2 ; tt[k] = sum_j T[k,j]^2 ; vt[k] = sum_j V[k,j]T[k,j]
__global__ __launch_bounds__(128) void gram_diag_kernel(
    const float* __restrict__ V, const float* __restrict__ T,
    float* __restrict__ vv, float* __restrict__ tt, float* __restrict__ vt)
{
    const int k = blockIdx.x;
    const int j = threadIdx.x;    // 0..127
    float v = V[(size_t)k * NF + j];
    float t = T[(size_t)k * NF + j];
    float a = v * v, b = t * t, c = v * t;
    #pragma unroll
    for (int off = 32; off > 0; off >>= 1) {
        a += __shfl_down(a, off, 64);
        b += __shfl_down(b, off, 64);
        c += __shfl_down(c, off, 64);
    }
    __shared__ float red[2][3];
    const int wave = j >> 6, lane = j & 63;
    if (lane == 0) { red[wave][0] = a; red[wave][1] = b; red[wave][2] = c; }
    __syncthreads();
    if (j == 0) {
        vv[k] = red[0][0] + red[1][0];
        tt[k] = red[0][1] + red[1][1];
        vt[k] = red[0][2] + red[1][2];
    }
}

// ---------------------------------------------------------------------------
// fp32 GEMM: G[b, 0:128] += A@V_rows, G[b, 128:256] += A@T_rows
// Block tile: 64 rows x 256 cols (full N), split-K over blockIdx.y.
// 256 threads, each computes 4 rows x 16 cols. Atomic accumulate into G.
__global__ __launch_bounds__(256) void gemm_full_kernel(
    const float* __restrict__ A, int lda, int Ksrc, int kChunk,
    const float* __restrict__ V, const float* __restrict__ T, int roff,
    float* __restrict__ G)
{
    __shared__ float As[32][68];     // [k][m], padded
    __shared__ float BsV[32][128];   // [k][n]
    __shared__ float BsT[32][128];

    const int tid = threadIdx.x;
    const int tx = tid & 15;         // col group 0..15
    const int ty = tid >> 4;         // row group 0..15
    const int m0 = blockIdx.x * 64;
    const int k0 = blockIdx.y * kChunk;
    const int k1 = min(k0 + kChunk, Ksrc);

    float acc[4][16];
    #pragma unroll
    for (int i = 0; i < 4; ++i)
        #pragma unroll
        for (int j = 0; j < 16; ++j) acc[i][j] = 0.f;

    for (int k = k0; k < k1; k += 32) {
        const int kw = min(32, k1 - k);   // always a multiple of 16 here
        // Load A tile: 64 rows x 32 k, float4 along k, store transposed
        #pragma unroll
        for (int it = 0; it < 2; ++it) {
            int idx = it * 256 + tid;     // 0..511
            int m   = idx >> 3;           // 0..63
            int k4  = (idx & 7) * 4;      // 0,4,..,28
            float4 av = make_float4(0.f, 0.f, 0.f, 0.f);
            if (k4 < kw)
                av = *(const float4*)&A[(size_t)(m0 + m) * lda + (k + k4)];
            As[k4 + 0][m] = av.x;
            As[k4 + 1][m] = av.y;
            As[k4 + 2][m] = av.z;
            As[k4 + 3][m] = av.w;
        }
        // Load B tiles (V and T): 32 k-rows x 128 cols each
        #pragma unroll
        for (int it = 0; it < 4; ++it) {
            int idx = it * 256 + tid;     // 0..1023
            int kk  = idx >> 5;           // 0..31
            int c4  = (idx & 31) * 4;     // 0,4,..,124
            float4 bv = make_float4(0.f, 0.f, 0.f, 0.f);
            float4 bt = make_float4(0.f, 0.f, 0.f, 0.f);
            if (kk < kw) {
                size_t row = (size_t)(roff + k + kk) * NF;
                bv = *(const float4*)&V[row + c4];
                bt = *(const float4*)&T[row + c4];
            }
            *(float4*)&BsV[kk][c4] = bv;
            *(float4*)&BsT[kk][c4] = bt;
        }
        __syncthreads();

        #pragma unroll
        for (int kk = 0; kk < 32; ++kk) {
            float4 a4 = *(const float4*)&As[kk][ty * 4];
            float av[4] = {a4.x, a4.y, a4.z, a4.w};
            float4 b0 = *(const float4*)&BsV[kk][tx * 4];
            float4 b1 = *(const float4*)&BsV[kk][64 + tx * 4];
            float4 b2 = *(const float4*)&BsT[kk][tx * 4];
            float4 b3 = *(const float4*)&BsT[kk][64 + tx * 4];
            float bv[16] = {b0.x,b0.y,b0.z,b0.w, b1.x,b1.y,b1.z,b1.w,
                            b2.x,b2.y,b2.z,b2.w, b3.x,b3.y,b3.z,b3.w};
            #pragma unroll
            for (int i = 0; i < 4; ++i)
                #pragma unroll
                for (int j = 0; j < 16; ++j)
                    acc[i][j] += av[i] * bv[j];
        }
        __syncthreads();
    }

    // Atomic accumulate into G. Col mapping: group g=j>>2 -> base g*64, then tx*4+(j&3).
    #pragma unroll
    for (int i = 0; i < 4; ++i) {
        const int row = m0 + ty * 4 + i;
        float* gr = G + (size_t)row * 256;
        #pragma unroll
        for (int j = 0; j < 16; ++j) {
            const int col = (j >> 2) * 64 + tx * 4 + (j & 3);
            atomic_add_f32(&gr[col], acc[i][j]);
        }
    }
}

// ---------------------------------------------------------------------------
// Per-row scalars for one source: S[b] = {a@vv, a@tt, a@vt, a@W, sum(a)}
__global__ __launch_bounds__(256) void row_scalars_kernel(
    const float* __restrict__ A, int Ksrc, int roff,
    const float* __restrict__ vv, const float* __restrict__ tt,
    const float* __restrict__ vt, const float* __restrict__ W,
    float* __restrict__ Sout)
{
    const int b = blockIdx.x;
    const float4* a4  = (const float4*)(A + (size_t)b * Ksrc);
    const float4* vv4 = (const float4*)(vv + roff);
    const float4* tt4 = (const float4*)(tt + roff);
    const float4* vt4 = (const float4*)(vt + roff);
    const float4* w4  = (const float4*)(W + roff);
    const int n4 = Ksrc >> 2;
    float s0 = 0.f, s1 = 0.f, s2 = 0.f, s3 = 0.f, s4 = 0.f;
    for (int i = threadIdx.x; i < n4; i += 256) {
        float4 x = a4[i];
        float4 q;
        q = vv4[i]; s0 += x.x*q.x + x.y*q.y + x.z*q.z + x.w*q.w;
        q = tt4[i]; s1 += x.x*q.x + x.y*q.y + x.z*q.z + x.w*q.w;
        q = vt4[i]; s2 += x.x*q.x + x.y*q.y + x.z*q.z + x.w*q.w;
        q = w4[i];  s3 += x.x*q.x + x.y*q.y + x.z*q.z + x.w*q.w;
        s4 += x.x + x.y + x.z + x.w;
    }
    #pragma unroll
    for (int off = 32; off > 0; off >>= 1) {
        s0 += __shfl_down(s0, off, 64);
        s1 += __shfl_down(s1, off, 64);
        s2 += __shfl_down(s2, off, 64);
        s3 += __shfl_down(s3, off, 64);
        s4 += __shfl_down(s4, off, 64);
    }
    __shared__ float red[4][5];
    const int wave = threadIdx.x >> 6, lane = threadIdx.x & 63;
    if (lane == 0) {
        red[wave][0] = s0; red[wave][1] = s1; red[wave][2] = s2;
        red[wave][3] = s3; red[wave][4] = s4;
    }
    __syncthreads();
    if (threadIdx.x == 0) {
        float* o = Sout + (size_t)b * 5;
        #pragma unroll
        for (int j = 0; j < 5; ++j)
            o[j] = red[0][j] + red[1][j] + red[2][j] + red[3][j];
    }
}

// ---------------------------------------------------------------------------
// Final combine: one wave per batch row.
__global__ __launch_bounds__(256) void epilogue_kernel(
    const float* __restrict__ G, const float* __restrict__ S,
    const float* __restrict__ bias, float* __restrict__ out)
{
    const int wave = threadIdx.x >> 6, lane = threadIdx.x & 63;
    const int b = blockIdx.x * 4 + wave;
    const float* Gs = G + (size_t)b * 256;
    const float* Gp = G + (size_t)B_ROWS * 256 + (size_t)b * 256;
    const float* Gn = G + (size_t)2 * B_ROWS * 256 + (size_t)b * 256;

    float t5p=0.f, t6p=0.f, dgp=0.f, t5n=0.f, t6n=0.f, dgn=0.f;
    #pragma unroll
    for (int jj = 0; jj < 2; ++jj) {
        int j = lane + jj * 64;
        float vxs = Gs[j],       txs = Gs[128 + j];
        float vxp = vxs + Gp[j], txp = txs + Gp[128 + j];
        float vxn = vxs + Gn[j], txn = txs + Gn[128 + j];
        t5p += vxp * vxp; t6p += txp * vxp; dgp += txp * txp;
        t5n += vxn * vxn; t6n += txn * vxn; dgn += txn * txn;
    }
    #pragma unroll
    for (int off = 32; off > 0; off >>= 1) {
        t5p += __shfl_down(t5p, off, 64); t6p += __shfl_down(t6p, off, 64);
        dgp += __shfl_down(dgp, off, 64); t5n += __shfl_down(t5n, off, 64);
        t6n += __shfl_down(t6n, off, 64); dgn += __shfl_down(dgn, off, 64);
    }
    if (lane == 0) {
        const float* Su = S + (size_t)b * 5;
        const float* Sp = S + (size_t)B_ROWS * 5 + (size_t)b * 5;      // x_prev
        const float* Sq = S + (size_t)2 * B_ROWS * 5 + (size_t)b * 5;  // x_pos
        const float* Sn = S + (size_t)3 * B_ROWS * 5 + (size_t)b * 5;  // x_neg
        const float bv = bias[0];

        // pos polarity
        float zvv = Su[0] + Sp[0] + Sq[0];
        float ztt = Su[1] + Sp[1] + Sq[1];
        float zvt = Su[2] + Sp[2] + Sq[2];
        float zs  = Su[4] + Sp[4] + Sq[4];
        float qp = 0.5f * (zs * zvv + 2.f * zs * ztt + 2.f * zs * zvt
                           - 2.f * t5p - 2.f * t6p) - 0.5f * dgp;
        // neg polarity
        float zvvn = Su[0] + Sp[0] + Sn[0];
        float zttn = Su[1] + Sp[1] + Sn[1];
        float zvtn = Su[2] + Sp[2] + Sn[2];
        float zsn  = Su[4] + Sp[4] + Sn[4];
        float qn = 0.5f * (zsn * zvvn + 2.f * zsn * zttn + 2.f * zsn * zvtn
                           - 2.f * t5n - 2.f * t6n) - 0.5f * dgn;

        // Faithful to reference: lin_neg used for BOTH outputs.
        float lin_n = Su[3] + Sp[3] + Sn[3] + bv;
        out[b]          = lin_n + qp;
        out[B_ROWS + b] = lin_n + qn;
    }
}

// ---------------------------------------------------------------------------
extern "C" void kernel_launch(void* const* d_in, const int* in_sizes, int n_in,
                              void* d_out, int out_size, void* d_ws, size_t ws_size,
                              hipStream_t stream) {
    const float* u     = (const float*)d_in[0];
    const float* xprev = (const float*)d_in[1];
    const float* xpos  = (const float*)d_in[2];
    const float* xneg  = (const float*)d_in[3];
    const float* V     = (const float*)d_in[4];
    const float* T     = (const float*)d_in[5];
    const float* W     = (const float*)d_in[6];
    const float* bias  = (const float*)d_in[7];
    float* out = (float*)d_out;

    float* ws = (float*)d_ws;
    float* vv = ws;
    float* tt = vv + KTOT;
    float* vt = tt + KTOT;
    float* G  = vt + KTOT;                       // 3 * B_ROWS * 256 floats
    float* S  = G + (size_t)3 * B_ROWS * 256;    // 4 * B_ROWS * 5 floats

    // Zero the atomic-accumulated GEMM buffer (ws is poisoned before each call).
    hipMemsetAsync(G, 0, (size_t)3 * B_ROWS * 256 * sizeof(float), stream);

    gram_diag_kernel<<<KTOT, 128, 0, stream>>>(V, T, vv, tt, vt);

    // GEMMs: split-K chunks are multiples of 32; last chunk handles remainder.
    dim3 blk(256);
    gemm_full_kernel<<<dim3(B_ROWS / 64, 16), blk, 0, stream>>>(
        u, UDIM, UDIM, 640, V, T, 0, G);                              // shared seg
    gemm_full_kernel<<<dim3(B_ROWS / 64, 16), blk, 0, stream>>>(
        xprev, XDIM, XDIM, 1280, V, T, UDIM, G);                      // shared seg
    gemm_full_kernel<<<dim3(B_ROWS / 64, 16), blk, 0, stream>>>(
        xpos, XDIM, XDIM, 1280, V, T, UDIM + XDIM, G + (size_t)B_ROWS * 256);
    gemm_full_kernel<<<dim3(B_ROWS / 64, 16), blk, 0, stream>>>(
        xneg, XDIM, XDIM, 1280, V, T, UDIM + XDIM, G + (size_t)2 * B_ROWS * 256);

    row_scalars_kernel<<<B_ROWS, 256, 0, stream>>>(u, UDIM, 0, vv, tt, vt, W, S);
    row_scalars_kernel<<<B_ROWS, 256, 0, stream>>>(xprev, XDIM, UDIM, vv, tt, vt, W,
                                                   S + (size_t)B_ROWS * 5);
    row_scalars_kernel<<<B_ROWS, 256, 0, stream>>>(xpos, XDIM, UDIM + XDIM, vv, tt, vt, W,
                                                   S + (size_t)2 * B_ROWS * 5);
    row_scalars_kernel<<<B_ROWS, 256, 0, stream>>>(xneg, XDIM, UDIM + XDIM, vv, tt, vt, W,
                                                   S + (size_t)3 * B_ROWS * 5);

    epilogue_kernel<<<B_ROWS / 4, 256, 0, stream>>>(G, S, bias, out);
}

// Round 2
// 1074.066 us; speedup vs baseline: 2.2069x; 2.2069x over previous
//
#include <hip/hip_runtime.h>
#include <hip/hip_bf16.h>

// Problem constants
#define B_ROWS 2048
#define UDIM   10000
#define XDIM   20000
#define KTOT   50000   // 2*XDIM + UDIM
#define NF     128

typedef __attribute__((ext_vector_type(8))) short bf16x8;
typedef __attribute__((ext_vector_type(8))) unsigned short us8;
typedef __attribute__((ext_vector_type(4))) float f32x4;

__device__ inline void atomic_add_f32(float* p, float v) {
#if defined(__AMDGCN__)
    unsafeAtomicAdd(p, v);
#else
    atomicAdd(p, v);
#endif
}

__device__ inline unsigned short f2bf(float x) {
    union { float f; unsigned u; } a; a.f = x;
    unsigned r = a.u + 0x7FFF + ((a.u >> 16) & 1);   // round-to-nearest-even
    return (unsigned short)(r >> 16);
}

// ---------------------------------------------------------------------------
// Prep: Bt[n][k] bf16, n in [0,256): rows 0..127 = V^T, 128..255 = T^T.
// Each block transposes a 64-k x 128-j tile of both V and T through LDS.
__global__ __launch_bounds__(256) void prep_bt_kernel(
    const float* __restrict__ V, const float* __restrict__ T,
    unsigned short* __restrict__ Bt)
{
    __shared__ unsigned short lv[NF][68];   // [j][k], pad 68 (136 B rows, 8B-aligned)
    __shared__ unsigned short lt[NF][68];
    const int k0 = blockIdx.x * 64;
    const int rows = min(64, KTOT - k0);

    for (int idx = threadIdx.x; idx < rows * 32; idx += 256) {
        int r  = idx >> 5;
        int j4 = (idx & 31) * 4;
        float4 v = *(const float4*)&V[(size_t)(k0 + r) * NF + j4];
        float4 t = *(const float4*)&T[(size_t)(k0 + r) * NF + j4];
        lv[j4 + 0][r] = f2bf(v.x); lv[j4 + 1][r] = f2bf(v.y);
        lv[j4 + 2][r] = f2bf(v.z); lv[j4 + 3][r] = f2bf(v.w);
        lt[j4 + 0][r] = f2bf(t.x); lt[j4 + 1][r] = f2bf(t.y);
        lt[j4 + 2][r] = f2bf(t.z); lt[j4 + 3][r] = f2bf(t.w);
    }
    __syncthreads();

    const int mat = threadIdx.x >> 7;     // 0 = V, 1 = T
    const int j   = threadIdx.x & 127;
    const unsigned short* src = mat ? &lt[j][0] : &lv[j][0];
    unsigned short* dst = Bt + (size_t)(mat * NF + j) * KTOT + k0;
    for (int c = 0; c < rows; c += 4)
        *(ushort4*)&dst[c] = *(const ushort4*)&src[c];
}

// ---------------------------------------------------------------------------
// vv[k], tt[k], vt[k] row-wise Gram diagonals (fp32 exact path)
__global__ __launch_bounds__(128) void gram_diag_kernel(
    const float* __restrict__ V, const float* __restrict__ T,
    float* __restrict__ vv, float* __restrict__ tt, float* __restrict__ vt)
{
    const int k = blockIdx.x;
    const int j = threadIdx.x;    // 0..127
    float v = V[(size_t)k * NF + j];
    float t = T[(size_t)k * NF + j];
    float a = v * v, b = t * t, c = v * t;
    #pragma unroll
    for (int off = 32; off > 0; off >>= 1) {
        a += __shfl_down(a, off, 64);
        b += __shfl_down(b, off, 64);
        c += __shfl_down(c, off, 64);
    }
    __shared__ float red[2][3];
    const int wave = j >> 6, lane = j & 63;
    if (lane == 0) { red[wave][0] = a; red[wave][1] = b; red[wave][2] = c; }
    __syncthreads();
    if (j == 0) {
        vv[k] = red[0][0] + red[1][0];
        tt[k] = red[0][1] + red[1][1];
        vt[k] = red[0][2] + red[1][2];
    }
}

// ---------------------------------------------------------------------------
// bf16 MFMA GEMM: G[m, n] += A[m, k0:k1] @ B[k, n]  (B given as Bt[n][k])
// Block tile 128x128, 4 waves (2x2), wave tile 64x64 via 16 mfma_16x16x32.
// Split-K over blockIdx.z, atomic fp32 accumulate into G (256 cols).
__global__ __launch_bounds__(256) void gemm_mfma_kernel(
    const float* __restrict__ A, int Ksrc, int kChunk,
    const unsigned short* __restrict__ Bt, int roff,
    float* __restrict__ G)
{
    __shared__ unsigned short As[128][40];   // [m][k], 80 B rows (16B-aligned)
    __shared__ unsigned short Bs[128][40];   // [n][k]

    const int tid  = threadIdx.x;
    const int lane = tid & 63;
    const int wave = tid >> 6;
    const int wm = (wave >> 1) * 64;
    const int wn = (wave & 1) * 64;
    const int fm = lane & 15;
    const int fq = lane >> 4;

    const int m0 = blockIdx.x * 128;
    const int n0 = blockIdx.y * 128;
    const int k0 = blockIdx.z * kChunk;
    const int k1 = min(k0 + kChunk, Ksrc);

    f32x4 acc[4][4];
    #pragma unroll
    for (int i = 0; i < 4; ++i)
        #pragma unroll
        for (int j = 0; j < 4; ++j)
            acc[i][j] = (f32x4){0.f, 0.f, 0.f, 0.f};

    for (int k = k0; k < k1; k += 32) {
        // Stage A: 128 rows x 32 k, fp32 -> bf16 (tail kw=16 zero-filled)
        #pragma unroll
        for (int it = 0; it < 4; ++it) {
            int idx = it * 256 + tid;          // 0..1023
            int m   = idx >> 3;                // 0..127
            int k4  = (idx & 7) * 4;           // 0,4,..,28
            ushort4 w = make_ushort4(0, 0, 0, 0);
            if (k + k4 < k1) {
                float4 av = *(const float4*)&A[(size_t)(m0 + m) * Ksrc + (k + k4)];
                w = make_ushort4(f2bf(av.x), f2bf(av.y), f2bf(av.z), f2bf(av.w));
            }
            *(ushort4*)&As[m][k4] = w;
        }
        // Stage B: 128 n-rows x 32 k bf16 from Bt (k-contiguous)
        {
            int n    = tid >> 1;
            int half = tid & 1;
            us8 z = (us8){0,0,0,0,0,0,0,0};
            us8 b0 = z, b1 = z;
            if (k + half * 16 < k1) {
                const unsigned short* src =
                    Bt + (size_t)(n0 + n) * KTOT + (roff + k + half * 16);
                b0 = *(const us8*)&src[0];
                b1 = *(const us8*)&src[8];
            }
            *(us8*)&Bs[n][half * 16 + 0] = b0;
            *(us8*)&Bs[n][half * 16 + 8] = b1;
        }
        __syncthreads();

        bf16x8 af[4], bf[4];
        #pragma unroll
        for (int i = 0; i < 4; ++i)
            af[i] = *(const bf16x8*)&As[wm + i * 16 + fm][fq * 8];
        #pragma unroll
        for (int j = 0; j < 4; ++j)
            bf[j] = *(const bf16x8*)&Bs[wn + j * 16 + fm][fq * 8];
        #pragma unroll
        for (int i = 0; i < 4; ++i)
            #pragma unroll
            for (int j = 0; j < 4; ++j)
                acc[i][j] = __builtin_amdgcn_mfma_f32_16x16x32_bf16(
                    af[i], bf[j], acc[i][j], 0, 0, 0);
        __syncthreads();
    }

    // Atomic accumulate: C/D layout col=lane&15, row=(lane>>4)*4+r
    #pragma unroll
    for (int i = 0; i < 4; ++i) {
        #pragma unroll
        for (int j = 0; j < 4; ++j) {
            const int col = n0 + wn + j * 16 + fm;
            #pragma unroll
            for (int r = 0; r < 4; ++r) {
                const int row = m0 + wm + i * 16 + fq * 4 + r;
                atomic_add_f32(&G[(size_t)row * 256 + col], acc[i][j][r]);
            }
        }
    }
}

// ---------------------------------------------------------------------------
// Per-row scalars for one source: S[b] = {a@vv, a@tt, a@vt, a@W, sum(a)} (fp32)
__global__ __launch_bounds__(256) void row_scalars_kernel(
    const float* __restrict__ A, int Ksrc, int roff,
    const float* __restrict__ vv, const float* __restrict__ tt,
    const float* __restrict__ vt, const float* __restrict__ W,
    float* __restrict__ Sout)
{
    const int b = blockIdx.x;
    const float4* a4  = (const float4*)(A + (size_t)b * Ksrc);
    const float4* vv4 = (const float4*)(vv + roff);
    const float4* tt4 = (const float4*)(tt + roff);
    const float4* vt4 = (const float4*)(vt + roff);
    const float4* w4  = (const float4*)(W + roff);
    const int n4 = Ksrc >> 2;
    float s0 = 0.f, s1 = 0.f, s2 = 0.f, s3 = 0.f, s4 = 0.f;
    for (int i = threadIdx.x; i < n4; i += 256) {
        float4 x = a4[i];
        float4 q;
        q = vv4[i]; s0 += x.x*q.x + x.y*q.y + x.z*q.z + x.w*q.w;
        q = tt4[i]; s1 += x.x*q.x + x.y*q.y + x.z*q.z + x.w*q.w;
        q = vt4[i]; s2 += x.x*q.x + x.y*q.y + x.z*q.z + x.w*q.w;
        q = w4[i];  s3 += x.x*q.x + x.y*q.y + x.z*q.z + x.w*q.w;
        s4 += x.x + x.y + x.z + x.w;
    }
    #pragma unroll
    for (int off = 32; off > 0; off >>= 1) {
        s0 += __shfl_down(s0, off, 64);
        s1 += __shfl_down(s1, off, 64);
        s2 += __shfl_down(s2, off, 64);
        s3 += __shfl_down(s3, off, 64);
        s4 += __shfl_down(s4, off, 64);
    }
    __shared__ float red[4][5];
    const int wave = threadIdx.x >> 6, lane = threadIdx.x & 63;
    if (lane == 0) {
        red[wave][0] = s0; red[wave][1] = s1; red[wave][2] = s2;
        red[wave][3] = s3; red[wave][4] = s4;
    }
    __syncthreads();
    if (threadIdx.x == 0) {
        float* o = Sout + (size_t)b * 5;
        #pragma unroll
        for (int j = 0; j < 5; ++j)
            o[j] = red[0][j] + red[1][j] + red[2][j] + red[3][j];
    }
}

// ---------------------------------------------------------------------------
// Final combine: one wave per batch row.
__global__ __launch_bounds__(256) void epilogue_kernel(
    const float* __restrict__ G, const float* __restrict__ S,
    const float* __restrict__ bias, float* __restrict__ out)
{
    const int wave = threadIdx.x >> 6, lane = threadIdx.x & 63;
    const int b = blockIdx.x * 4 + wave;
    const float* Gs = G + (size_t)b * 256;
    const float* Gp = G + (size_t)B_ROWS * 256 + (size_t)b * 256;
    const float* Gn = G + (size_t)2 * B_ROWS * 256 + (size_t)b * 256;

    float t5p=0.f, t6p=0.f, dgp=0.f, t5n=0.f, t6n=0.f, dgn=0.f;
    #pragma unroll
    for (int jj = 0; jj < 2; ++jj) {
        int j = lane + jj * 64;
        float vxs = Gs[j],       txs = Gs[128 + j];
        float vxp = vxs + Gp[j], txp = txs + Gp[128 + j];
        float vxn = vxs + Gn[j], txn = txs + Gn[128 + j];
        t5p += vxp * vxp; t6p += txp * vxp; dgp += txp * txp;
        t5n += vxn * vxn; t6n += txn * vxn; dgn += txn * txn;
    }
    #pragma unroll
    for (int off = 32; off > 0; off >>= 1) {
        t5p += __shfl_down(t5p, off, 64); t6p += __shfl_down(t6p, off, 64);
        dgp += __shfl_down(dgp, off, 64); t5n += __shfl_down(t5n, off, 64);
        t6n += __shfl_down(t6n, off, 64); dgn += __shfl_down(dgn, off, 64);
    }
    if (lane == 0) {
        const float* Su = S + (size_t)b * 5;
        const float* Sp = S + (size_t)B_ROWS * 5 + (size_t)b * 5;
        const float* Sq = S + (size_t)2 * B_ROWS * 5 + (size_t)b * 5;
        const float* Sn = S + (size_t)3 * B_ROWS * 5 + (size_t)b * 5;
        const float bv = bias[0];

        float zvv = Su[0] + Sp[0] + Sq[0];
        float ztt = Su[1] + Sp[1] + Sq[1];
        float zvt = Su[2] + Sp[2] + Sq[2];
        float zs  = Su[4] + Sp[4] + Sq[4];
        float qp = 0.5f * (zs * zvv + 2.f * zs * ztt + 2.f * zs * zvt
                           - 2.f * t5p - 2.f * t6p) - 0.5f * dgp;

        float zvvn = Su[0] + Sp[0] + Sn[0];
        float zttn = Su[1] + Sp[1] + Sn[1];
        float zvtn = Su[2] + Sp[2] + Sn[2];
        float zsn  = Su[4] + Sp[4] + Sn[4];
        float qn = 0.5f * (zsn * zvvn + 2.f * zsn * zttn + 2.f * zsn * zvtn
                           - 2.f * t5n - 2.f * t6n) - 0.5f * dgn;

        float lin_n = Su[3] + Sp[3] + Sn[3] + bv;
        out[b]          = lin_n + qp;
        out[B_ROWS + b] = lin_n + qn;
    }
}

// ---------------------------------------------------------------------------
extern "C" void kernel_launch(void* const* d_in, const int* in_sizes, int n_in,
                              void* d_out, int out_size, void* d_ws, size_t ws_size,
                              hipStream_t stream) {
    const float* u     = (const float*)d_in[0];
    const float* xprev = (const float*)d_in[1];
    const float* xpos  = (const float*)d_in[2];
    const float* xneg  = (const float*)d_in[3];
    const float* V     = (const float*)d_in[4];
    const float* T     = (const float*)d_in[5];
    const float* W     = (const float*)d_in[6];
    const float* bias  = (const float*)d_in[7];
    float* out = (float*)d_out;

    // Workspace layout
    unsigned short* Bt = (unsigned short*)d_ws;            // 256*KTOT bf16 = 25.6 MB
    float* vv = (float*)(Bt + (size_t)256 * KTOT);         // KTOT
    float* tt = vv + KTOT;
    float* vt = tt + KTOT;
    float* G  = vt + KTOT;                                 // 3 * B_ROWS * 256
    float* S  = G + (size_t)3 * B_ROWS * 256;              // 4 * B_ROWS * 5

    hipMemsetAsync(G, 0, (size_t)3 * B_ROWS * 256 * sizeof(float), stream);

    prep_bt_kernel<<<(KTOT + 63) / 64, 256, 0, stream>>>(V, T, Bt);
    gram_diag_kernel<<<KTOT, 128, 0, stream>>>(V, T, vv, tt, vt);

    // MFMA GEMMs (split-K=16; chunks are multiples of 32)
    dim3 blk(256);
    gemm_mfma_kernel<<<dim3(16, 2, 16), blk, 0, stream>>>(
        u, UDIM, 640, Bt, 0, G);                                        // shared seg
    gemm_mfma_kernel<<<dim3(16, 2, 16), blk, 0, stream>>>(
        xprev, XDIM, 1280, Bt, UDIM, G);                                // shared seg
    gemm_mfma_kernel<<<dim3(16, 2, 16), blk, 0, stream>>>(
        xpos, XDIM, 1280, Bt, UDIM + XDIM, G + (size_t)B_ROWS * 256);
    gemm_mfma_kernel<<<dim3(16, 2, 16), blk, 0, stream>>>(
        xneg, XDIM, 1280, Bt, UDIM + XDIM, G + (size_t)2 * B_ROWS * 256);

    row_scalars_kernel<<<B_ROWS, 256, 0, stream>>>(u, UDIM, 0, vv, tt, vt, W, S);
    row_scalars_kernel<<<B_ROWS, 256, 0, stream>>>(xprev, XDIM, UDIM, vv, tt, vt, W,
                                                   S + (size_t)B_ROWS * 5);
    row_scalars_kernel<<<B_ROWS, 256, 0, stream>>>(xpos, XDIM, UDIM + XDIM, vv, tt, vt, W,
                                                   S + (size_t)2 * B_ROWS * 5);
    row_scalars_kernel<<<B_ROWS, 256, 0, stream>>>(xneg, XDIM, UDIM + XDIM, vv, tt, vt, W,
                                                   S + (size_t)3 * B_ROWS * 5);

    epilogue_kernel<<<B_ROWS / 4, 256, 0, stream>>>(G, S, bias, out);
}